// Round 13
// baseline (1225.763 us; speedup 1.0000x reference)
//
#include <hip/hip_runtime.h>
#include <stdint.h>

// y[m,o] = sum_k x[m,k]*(W8[o,k]-zero[o])*scale[o] + bias[o], M=8192 N=11008 K=4096.
// x ~= xs_m*(128*h + l) (h,l int8); G = xs_m*(128*Gh + Gl) via two i8 MFMA GEMMs
// sharing B-frags; y = scale*G - scale*zero*rowsum + bias.
// R13: SHARED-NOTHING, BARRIER-FREE waves. Block 128x128, 4 waves; each wave
// owns a 64x64 output quadrant and privately stages its own A-rows (hi+lo) and
// B-cols per BK=64 into a per-wave ring-3 LDS region (3x12KB; 144KB/block,
// 1 block/CU). No wave reads another wave's LDS => NO barriers anywhere; the
// only sync is each wave's own vmcnt(24) (ring-3: waits loads issued 2 tiles
// ~1900cyc ago). Dummy-restage of the final tile keeps vmcnt(24) uniform.
// 64B-row additive swizzle pair (R8: measured 0 conflicts), tid->lane.

#define M_DIM 8192
#define N_DIM 11008
#define K_DIM 4096
#define NTT   (K_DIM / 64)    // 64 K-tiles of 64
#define WREG  36864           // per-wave LDS region: 3 slots x 12KB
#define SLOTB 12288           // slot: Ah 4K | Al 4K | B 4K

typedef __attribute__((ext_vector_type(4))) int i32x4;

// ---------------- prep kernels ----------------

__global__ void convert_w_kernel(const int* __restrict__ w,
                                 int8_t* __restrict__ o, int n4) {
  int idx = blockIdx.x * blockDim.x + threadIdx.x;
  int stride = gridDim.x * blockDim.x;
  for (int i = idx; i < n4; i += stride) {
    int4 v = ((const int4*)w)[i];
    int r = (v.x & 255) | ((v.y & 255) << 8) | ((v.z & 255) << 16) | ((v.w & 255) << 24);
    ((int*)o)[i] = r;
  }
}

__global__ __launch_bounds__(256) void quantx_kernel(
    const float* __restrict__ x, int8_t* __restrict__ h8, int8_t* __restrict__ l8,
    float* __restrict__ xs, float* __restrict__ rsum) {
  const int row = blockIdx.x;
  const int t = threadIdx.x;
  const float4* px = (const float4*)(x + (size_t)row * K_DIM);
  float4 v[4];
  float mx = 0.f, sm = 0.f;
  #pragma unroll
  for (int i = 0; i < 4; ++i) {
    v[i] = px[i * 256 + t];
    mx = fmaxf(mx, fmaxf(fmaxf(fabsf(v[i].x), fabsf(v[i].y)),
                         fmaxf(fabsf(v[i].z), fabsf(v[i].w))));
    sm += v[i].x + v[i].y + v[i].z + v[i].w;
  }
  #pragma unroll
  for (int off = 32; off > 0; off >>= 1) {
    mx = fmaxf(mx, __shfl_down(mx, off));
    sm += __shfl_down(sm, off);
  }
  __shared__ float rmx[4], rsm[4];
  const int wv = t >> 6, ln = t & 63;
  if (ln == 0) { rmx[wv] = mx; rsm[wv] = sm; }
  __syncthreads();
  const float rowmax = fmaxf(fmaxf(rmx[0], rmx[1]), fmaxf(rmx[2], rmx[3]));
  if (t == 0) {
    xs[row] = rowmax > 0.f ? rowmax / 16256.f : 0.f;
    rsum[row] = rsm[0] + rsm[1] + rsm[2] + rsm[3];
  }
  const float inv = rowmax > 0.f ? 16256.f / rowmax : 0.f;
  int* hp = (int*)(h8 + (size_t)row * K_DIM);
  int* lp = (int*)(l8 + (size_t)row * K_DIM);
  #pragma unroll
  for (int i = 0; i < 4; ++i) {
    int q0 = (int)rintf(v[i].x * inv);
    int q1 = (int)rintf(v[i].y * inv);
    int q2 = (int)rintf(v[i].z * inv);
    int q3 = (int)rintf(v[i].w * inv);
    int h0 = (q0 + 64) >> 7, h1 = (q1 + 64) >> 7, h2 = (q2 + 64) >> 7, h3 = (q3 + 64) >> 7;
    int l0 = q0 - (h0 << 7), l1 = q1 - (h1 << 7), l2 = q2 - (h2 << 7), l3 = q3 - (h3 << 7);
    hp[i * 256 + t] = (h0 & 255) | ((h1 & 255) << 8) | ((h2 & 255) << 16) | ((h3 & 255) << 24);
    lp[i * 256 + t] = (l0 & 255) | ((l1 & 255) << 8) | ((l2 & 255) << 16) | ((l3 & 255) << 24);
  }
}

// ---------------- main GEMM ----------------

// per-wave private stage of one BK=64 tile: 12 x global_load_lds (1KB each).
// load r of array X: lane l -> LDS byte r*1024 + l*16 = row (r*16 + l>>2),
// phys slot (l&3). Global col = ((l&3) - ((l>>3)&3)) & 3 (inverse of read swz;
// (row>>1)&3 == (l>>3)&3 since r*16>>1 = r*8 === 0 mod 4).
__device__ __forceinline__ void stage64(
    const int8_t* __restrict__ Ah, const int8_t* __restrict__ Al,
    const int8_t* __restrict__ Bw, size_t a_base, size_t b_base,
    int h, int srow, int scol, int8_t* slotbuf) {
  const int ks = h * 64;
  #pragma unroll
  for (int r = 0; r < 4; ++r) {
    const size_t off = (size_t)(r * 16 + srow) * K_DIM + ks + scol;
    const int8_t* ga = Ah + a_base + off;
    const int8_t* gl = Al + a_base + off;
    const int8_t* gb = Bw + b_base + off;
    __builtin_amdgcn_global_load_lds((const __attribute__((address_space(1))) void*)ga,
        (__attribute__((address_space(3))) void*)(slotbuf + r * 1024), 16, 0, 0);
    __builtin_amdgcn_global_load_lds((const __attribute__((address_space(1))) void*)gl,
        (__attribute__((address_space(3))) void*)(slotbuf + 4096 + r * 1024), 16, 0, 0);
    __builtin_amdgcn_global_load_lds((const __attribute__((address_space(1))) void*)gb,
        (__attribute__((address_space(3))) void*)(slotbuf + 8192 + r * 1024), 16, 0, 0);
  }
}

__global__ __launch_bounds__(256) void qgemm_kernel(
    const int8_t* __restrict__ Ah, const int8_t* __restrict__ Al,
    const int8_t* __restrict__ Bw, const float* __restrict__ xs,
    const float* __restrict__ rowsum, const float* __restrict__ scale,
    const float* __restrict__ zero, const float* __restrict__ bias,
    float* __restrict__ out) {
  extern __shared__ int8_t smem[];  // 4 waves x 36KB private rings

  const int tid = threadIdx.x;
  const int wave = tid >> 6;
  const int lane = tid & 63;

  // XCD-chunked + grouped: nwg = 5504 = 8 x 688 (bijective)
  const int bid = blockIdx.x;
  const int wg = (bid & 7) * 688 + (bid >> 3);
  const int group = wg / 688;
  const int rem = wg % 688;
  const int bm = group * 8 + (rem & 7);  // 0..63 (M/128)
  const int bn = rem >> 3;               // 0..85 (N/128)

  const int wr = wave >> 1;  // 0..1: 64-row half
  const int wc = wave & 1;   // 0..1: 64-col half

  int8_t* wbase = smem + wave * WREG;

  i32x4 acch[4][4], accl[4][4];
  #pragma unroll
  for (int i = 0; i < 4; ++i)
    #pragma unroll
    for (int j = 0; j < 4; ++j) {
      acch[i][j] = (i32x4){0, 0, 0, 0};
      accl[i][j] = (i32x4){0, 0, 0, 0};
    }

  // staging addressing (per-wave private slices)
  const int srow = lane >> 2;                                     // 0..15
  const int scol = ((((lane & 3) - ((lane >> 3) & 3)) & 3) << 4); // global byte col
  const size_t a_base = (size_t)(bm * 128 + wr * 64) * K_DIM;
  const size_t b_base = (size_t)(bn * 128 + wc * 64) * K_DIM;

  // fragment reads (64B rows, 4 slots): phys slot = (g + (row>>1)) & 3;
  // (row>>1)&3 == (fr>>1)&3 for fragment rows mi*16+fr (R8: 0 conflicts).
  const int fr = lane & 15;
  const int g = lane >> 4;
  const int scA = (((g + (fr >> 1)) & 3) << 4);
  int arow[4];
  #pragma unroll
  for (int i = 0; i < 4; ++i) arow[i] = (i * 16 + fr) * 64 + scA;

  // prologue: stage tiles 0,1 into slots 0,1 (private -> no syncs at all)
  stage64(Ah, Al, Bw, a_base, b_base, 0, srow, scol, wbase);
  stage64(Ah, Al, Bw, a_base, b_base, 1, srow, scol, wbase + SLOTB);

  int slot_cur = 0, slot_stage = 2;

  #pragma unroll 1
  for (int t = 0; t < NTT; ++t) {
    // stage tile t+2 (dummy-restage last tile to keep vmcnt uniform)
    const int hs = (t + 2 < NTT) ? (t + 2) : (NTT - 1);
    stage64(Ah, Al, Bw, a_base, b_base, hs, srow, scol, wbase + slot_stage * SLOTB);

    // own loads for tile t complete (24 newer: tiles t+1, t+2 in flight)
    asm volatile("s_waitcnt vmcnt(24)" ::: "memory");

    const int8_t* p = wbase + slot_cur * SLOTB;
    i32x4 bf[4];
    #pragma unroll
    for (int ni = 0; ni < 4; ++ni)
      bf[ni] = *(const i32x4*)(p + 8192 + arow[ni]);  // B rows: ni*16+fr, same formula

    i32x4 aX0 = *(const i32x4*)(p + arow[0]);
    i32x4 aX1 = *(const i32x4*)(p + 4096 + arow[0]);
    #pragma unroll
    for (int mi = 0; mi < 4; ++mi) {
      i32x4 aY0 = aX0, aY1 = aX1;
      if (mi < 3) {
        aY0 = *(const i32x4*)(p + arow[mi + 1]);
        aY1 = *(const i32x4*)(p + 4096 + arow[mi + 1]);
      }
      #pragma unroll
      for (int ni = 0; ni < 4; ++ni)
        acch[mi][ni] = __builtin_amdgcn_mfma_i32_16x16x64_i8(aX0, bf[ni], acch[mi][ni], 0, 0, 0);
      #pragma unroll
      for (int ni = 0; ni < 4; ++ni)
        accl[mi][ni] = __builtin_amdgcn_mfma_i32_16x16x64_i8(aX1, bf[ni], accl[mi][ni], 0, 0, 0);
      aX0 = aY0; aX1 = aY1;
    }

    slot_cur = (slot_cur == 2) ? 0 : slot_cur + 1;
    slot_stage = (slot_stage == 2) ? 0 : slot_stage + 1;
  }

  // epilogue: G = xs_m*(128*Gh + Gl); y = scale*G - scale*zero*rowsum + bias
  // C/D 16x16: col = lane&15, row = (lane>>4)*4 + j
  const int row0 = bm * 128 + wr * 64;
  const int col0 = bn * 128 + wc * 64;
  float s_[4], sz_[4], b_[4];
  #pragma unroll
  for (int ni = 0; ni < 4; ++ni) {
    const int n = col0 + ni * 16 + fr;
    const float s = scale[n];
    s_[ni] = s;
    sz_[ni] = s * zero[n];
    b_[ni] = bias[n];
  }
  #pragma unroll
  for (int mi = 0; mi < 4; ++mi) {
    #pragma unroll
    for (int j = 0; j < 4; ++j) {
      const int m = row0 + mi * 16 + g * 4 + j;
      const float xsm = xs[m];
      const float rs = rowsum[m];
      float* po = out + (size_t)m * N_DIM + col0;
      #pragma unroll
      for (int ni = 0; ni < 4; ++ni) {
        const float G = xsm * (128.f * (float)acch[mi][ni][j] + (float)accl[mi][ni][j]);
        po[ni * 16 + fr] = s_[ni] * G - sz_[ni] * rs + b_[ni];
      }
    }
  }
}

// ---------------- fallback (only if workspace too small) ----------------

__global__ void fallback_kernel(const float* __restrict__ x, const int* __restrict__ w,
                                const float* __restrict__ scale, const float* __restrict__ zero,
                                const float* __restrict__ bias, float* __restrict__ out) {
  const int n = blockIdx.x * 16 + (threadIdx.x & 15);
  const int m = blockIdx.y * 16 + (threadIdx.x >> 4);
  const float z = zero[n];
  const float* xr = x + (size_t)m * K_DIM;
  const int* wr = w + (size_t)n * K_DIM;
  float acc = 0.f;
  for (int k = 0; k < K_DIM; ++k) acc += xr[k] * ((float)wr[k] - z);
  out[(size_t)m * N_DIM + n] = scale[n] * acc + bias[n];
}

// ---------------- launch ----------------

extern "C" void kernel_launch(void* const* d_in, const int* in_sizes, int n_in,
                              void* d_out, int out_size, void* d_ws, size_t ws_size,
                              hipStream_t stream) {
  const float* x     = (const float*)d_in[0];
  const int*   w     = (const int*)d_in[1];
  const float* scale = (const float*)d_in[2];
  const float* zero  = (const float*)d_in[3];
  const float* bias  = (const float*)d_in[4];
  float* out = (float*)d_out;

  const size_t n_x = (size_t)M_DIM * K_DIM;
  const size_t n_w = (size_t)N_DIM * K_DIM;
  const size_t need = n_x * 2 + n_w + (size_t)M_DIM * 8;  // ~112 MB

  if (ws_size < need) {
    dim3 gr(N_DIM / 16, M_DIM / 16);
    fallback_kernel<<<gr, 256, 0, stream>>>(x, w, scale, zero, bias, out);
    return;
  }

  int8_t* x_h = (int8_t*)d_ws;
  int8_t* x_l = x_h + n_x;
  int8_t* w_8 = x_l + n_x;
  float* rsum = (float*)(w_8 + n_w);
  float* xs   = rsum + M_DIM;

  convert_w_kernel<<<2048, 256, 0, stream>>>(w, w_8, (int)(n_w / 4));
  quantx_kernel<<<M_DIM, 256, 0, stream>>>(x, x_h, x_l, xs, rsum);

  (void)hipFuncSetAttribute((const void*)qgemm_kernel,
                            hipFuncAttributeMaxDynamicSharedMemorySize, 4 * WREG);

  const int nblocks = (M_DIM / 128) * (N_DIM / 128);  // 64 * 86 = 5504
  qgemm_kernel<<<nblocks, 256, 4 * WREG, stream>>>(x_h, x_l, w_8, xs, rsum,
                                                   scale, zero, bias, out);
}